// Round 1
// baseline (302.651 us; speedup 1.0000x reference)
//
#include <hip/hip_runtime.h>
#include <stdint.h>

#define NB 8
#define ND 2048
#define NH 256
#define MROWS (NB*ND)   // 16384

typedef __attribute__((ext_vector_type(8))) short bf16x8;
typedef __attribute__((ext_vector_type(4))) float f32x4;
typedef __attribute__((ext_vector_type(4))) int   i32x4;
typedef __attribute__((ext_vector_type(2))) unsigned int u32x2;
typedef __attribute__((ext_vector_type(4))) unsigned int u32x4;

#define MFMA16 __builtin_amdgcn_mfma_f32_16x16x32_bf16

__device__ __forceinline__ unsigned short f2bf(float f) {
    union { float f; unsigned int u; } c; c.f = f;
    unsigned int u = c.u + 0x7FFFu + ((c.u >> 16) & 1u);
    return (unsigned short)(u >> 16);
}
__device__ __forceinline__ unsigned int pack2(float a, float b) {
    return (unsigned int)f2bf(a) | ((unsigned int)f2bf(b) << 16);
}

// ---------------------------------------------------------------------------
// Kernel 1: q = x@Wq^T, k = x@Wk^T (row-major bf16), vT[o][d] = (x@Wv^T)^T
// C = mfma(A,B): A rows give output rows, both operands row-major k-contig.
// z<2: A=W (rows o), B=x (rows m)  -> D: col=m, rows=o -> q/k row-major packed
// z=2: A=x (rows d), B=Wv (rows o) -> D: col=o, rows=d -> vT[o][d] packed
// ---------------------------------------------------------------------------
__global__ __launch_bounds__(256) void qkv_kernel(
    const float* __restrict__ x,
    const float* __restrict__ Wq, const float* __restrict__ Wk, const float* __restrict__ Wv,
    unsigned short* __restrict__ qb, unsigned short* __restrict__ kb, unsigned short* __restrict__ vT)
{
    __shared__ unsigned short Wt[64][264];
    __shared__ unsigned short Xt[64][264];
    const int z  = blockIdx.z;
    const int m0 = blockIdx.x * 64;   // rows of x (bd)
    const int o0 = blockIdx.y * 64;   // rows of W (output features)
    const float* W = (z == 0) ? Wq : (z == 1 ? Wk : Wv);
    const int t = threadIdx.x;

#pragma unroll
    for (int i = 0; i < 16; ++i) {
        int fidx = i * 256 + t;
        int row = fidx >> 6, c4 = fidx & 63;
        f32x4 vW = *reinterpret_cast<const f32x4*>(W + (size_t)(o0 + row) * NH + c4 * 4);
        f32x4 vX = *reinterpret_cast<const f32x4*>(x + (size_t)(m0 + row) * NH + c4 * 4);
        u32x2 pw; pw[0] = pack2(vW[0], vW[1]); pw[1] = pack2(vW[2], vW[3]);
        u32x2 px; px[0] = pack2(vX[0], vX[1]); px[1] = pack2(vX[2], vX[3]);
        *reinterpret_cast<u32x2*>(&Wt[row][c4 * 4]) = pw;
        *reinterpret_cast<u32x2*>(&Xt[row][c4 * 4]) = px;
    }
    __syncthreads();

    const int w = t >> 6, lane = t & 63, lr = lane & 15, half = lane >> 4;
    const unsigned short (*Ab)[264] = (z < 2) ? Wt : Xt;
    const unsigned short (*Bb)[264] = (z < 2) ? Xt : Wt;
    const int ar0 = 32 * (w >> 1), br0 = 32 * (w & 1);

    f32x4 acc[2][2] = {};
#pragma unroll
    for (int kk = 0; kk < 8; ++kk) {
        bf16x8 a[2], bfr[2];
#pragma unroll
        for (int f = 0; f < 2; ++f) {
            a[f]   = *reinterpret_cast<const bf16x8*>(&Ab[ar0 + 16 * f + lr][32 * kk + 8 * half]);
            bfr[f] = *reinterpret_cast<const bf16x8*>(&Bb[br0 + 16 * f + lr][32 * kk + 8 * half]);
        }
#pragma unroll
        for (int fa = 0; fa < 2; ++fa)
#pragma unroll
            for (int fb = 0; fb < 2; ++fb)
                acc[fa][fb] = MFMA16(a[fa], bfr[fb], acc[fa][fb], 0, 0, 0);
    }

    if (z < 2) {
        unsigned short* dst = z ? kb : qb;
#pragma unroll
        for (int fa = 0; fa < 2; ++fa)
#pragma unroll
            for (int fb = 0; fb < 2; ++fb) {
                int m = m0 + br0 + 16 * fb + lr;
                int o = o0 + ar0 + 16 * fa + 4 * half;
                u32x2 pk; pk[0] = pack2(acc[fa][fb][0], acc[fa][fb][1]);
                pk[1] = pack2(acc[fa][fb][2], acc[fa][fb][3]);
                *reinterpret_cast<u32x2*>(dst + (size_t)m * NH + o) = pk;
            }
    } else {
#pragma unroll
        for (int fa = 0; fa < 2; ++fa)
#pragma unroll
            for (int fb = 0; fb < 2; ++fb) {
                int dg = m0 + ar0 + 16 * fa + 4 * half;  // global bd row
                int o  = o0 + br0 + 16 * fb + lr;
                int bb = dg >> 11, di = dg & 2047;
                u32x2 pk; pk[0] = pack2(acc[fa][fb][0], acc[fa][fb][1]);
                pk[1] = pack2(acc[fa][fb][2], acc[fa][fb][3]);
                *reinterpret_cast<u32x2*>(vT + ((size_t)bb * NH + o) * ND + di) = pk;
            }
    }
}

// ---------------------------------------------------------------------------
// Kernel 2: flash attention. Block = 4 waves, one batch b, 64 q-rows.
// Wave w owns q rows [qt*64+16w, +16). S^T = mfma(K_rows, Q_rows):
// lane holds col d = lane&15 (fixed q row) -> per-lane online softmax,
// lane-uniform rescale of PV accumulator. P^T via 1KB per-wave LDS.
// ---------------------------------------------------------------------------
__global__ __launch_bounds__(256) void attn_kernel(
    const unsigned short* __restrict__ qb, const unsigned short* __restrict__ kb,
    const unsigned short* __restrict__ vT, const int* __restrict__ adj,
    unsigned short* __restrict__ agg)
{
    __shared__ unsigned short p_lds[4][16][32];
    const int bid = blockIdx.x;
    const int b = bid & 7, qt = bid >> 3;          // XCD-swizzle: batch per XCD
    const int t = threadIdx.x, w = t >> 6, lane = t & 63, lr = lane & 15, half = lane >> 4;
    const int d_local = qt * 64 + w * 16 + lr;     // this lane's q row (column of S^T)
    const size_t qrow = ((size_t)b * ND + d_local) * NH;

    bf16x8 qf[8];
#pragma unroll
    for (int kk = 0; kk < 8; ++kk)
        qf[kk] = *reinterpret_cast<const bf16x8*>(qb + qrow + 32 * kk + 8 * half);

    f32x4 acc[16] = {};
    float m_run = -__builtin_inff(), l_run = 0.f;
    const float SC = 0.0625f, L2E = 1.44269504f;

    for (int et = 0; et < 64; ++et) {
        const int e0 = et * 32;
        f32x4 s[2] = {};
#pragma unroll
        for (int kk = 0; kk < 8; ++kk) {
            bf16x8 k0 = *reinterpret_cast<const bf16x8*>(kb + ((size_t)b * ND + e0 + lr) * NH + 32 * kk + 8 * half);
            bf16x8 k1 = *reinterpret_cast<const bf16x8*>(kb + ((size_t)b * ND + e0 + 16 + lr) * NH + 32 * kk + 8 * half);
            s[0] = MFMA16(k0, qf[kk], s[0], 0, 0, 0);
            s[1] = MFMA16(k1, qf[kk], s[1], 0, 0, 0);
        }

        float pv[2][4];
        float tmax = -__builtin_inff();
#pragma unroll
        for (int fe = 0; fe < 2; ++fe) {
            i32x4 aj = *reinterpret_cast<const i32x4*>(adj + ((size_t)b * ND + d_local) * ND + e0 + 16 * fe + 4 * half);
#pragma unroll
            for (int r = 0; r < 4; ++r) {
                float sv = s[fe][r] * SC;
                sv = (aj[r] > 0) ? sv : -1e9f;
                pv[fe][r] = sv;
                tmax = fmaxf(tmax, sv);
            }
        }
        tmax = fmaxf(tmax, __shfl_xor(tmax, 16));
        tmax = fmaxf(tmax, __shfl_xor(tmax, 32));
        const float m_new = fmaxf(m_run, tmax);
        const float scale = exp2f((m_run - m_new) * L2E);
        float psum = 0.f;
#pragma unroll
        for (int fe = 0; fe < 2; ++fe)
#pragma unroll
            for (int r = 0; r < 4; ++r) {
                float p = exp2f((pv[fe][r] - m_new) * L2E);
                pv[fe][r] = p;
                psum += p;
            }
        psum += __shfl_xor(psum, 16);
        psum += __shfl_xor(psum, 32);
        l_run = l_run * scale + psum;
        m_run = m_new;
#pragma unroll
        for (int fo = 0; fo < 16; ++fo)
#pragma unroll
            for (int r = 0; r < 4; ++r) acc[fo][r] *= scale;

        // P^T (bf16) -> per-wave LDS [d][e]
#pragma unroll
        for (int fe = 0; fe < 2; ++fe) {
            u32x2 pk; pk[0] = pack2(pv[fe][0], pv[fe][1]); pk[1] = pack2(pv[fe][2], pv[fe][3]);
            *reinterpret_cast<u32x2*>(&p_lds[w][lr][16 * fe + 4 * half]) = pk;
        }
        bf16x8 pf = *reinterpret_cast<const bf16x8*>(&p_lds[w][lr][8 * half]);

#pragma unroll
        for (int fo = 0; fo < 16; ++fo) {
            bf16x8 av = *reinterpret_cast<const bf16x8*>(vT + ((size_t)b * NH + 16 * fo + lr) * ND + e0 + 8 * half);
            acc[fo] = MFMA16(av, pf, acc[fo], 0, 0, 0);
        }
    }

    const float inv = 1.f / l_run;
    const size_t mrow = ((size_t)b * ND + d_local) * NH;
#pragma unroll
    for (int fo = 0; fo < 16; ++fo) {
        u32x2 pk; pk[0] = pack2(acc[fo][0] * inv, acc[fo][1] * inv);
        pk[1] = pack2(acc[fo][2] * inv, acc[fo][3] * inv);
        *reinterpret_cast<u32x2*>(agg + mrow + 16 * fo + 4 * half) = pk;
    }
}

// ---------------------------------------------------------------------------
// Kernel 3a: h = agg @ Wp^T + bp + x   (f32 out, float4 stores)
// A = Wp (rows p), B = agg (rows m) -> D: col=m, rows=p -> h[m][p] packed f32x4
// ---------------------------------------------------------------------------
__global__ __launch_bounds__(256) void oproj_kernel(
    const unsigned short* __restrict__ agg, const float* __restrict__ Wp,
    const float* __restrict__ bp, const float* __restrict__ x, float* __restrict__ h)
{
    __shared__ unsigned short Wt[64][264];
    __shared__ unsigned short Xt[64][264];
    const int m0 = blockIdx.x * 64, p0 = blockIdx.y * 64;
    const int t = threadIdx.x;

#pragma unroll
    for (int i = 0; i < 16; ++i) {
        int fidx = i * 256 + t, row = fidx >> 6, c4 = fidx & 63;
        f32x4 vW = *reinterpret_cast<const f32x4*>(Wp + (size_t)(p0 + row) * NH + c4 * 4);
        u32x2 pw; pw[0] = pack2(vW[0], vW[1]); pw[1] = pack2(vW[2], vW[3]);
        *reinterpret_cast<u32x2*>(&Wt[row][c4 * 4]) = pw;
    }
#pragma unroll
    for (int i = 0; i < 8; ++i) {
        int fidx = i * 256 + t, row = fidx >> 5, c8 = fidx & 31;
        u32x4 vA = *reinterpret_cast<const u32x4*>(agg + (size_t)(m0 + row) * NH + c8 * 8);
        *reinterpret_cast<u32x4*>(&Xt[row][c8 * 8]) = vA;
    }
    __syncthreads();

    const int w = t >> 6, lane = t & 63, lr = lane & 15, half = lane >> 4;
    const int ar0 = 32 * (w >> 1), br0 = 32 * (w & 1);

    f32x4 acc[2][2] = {};
#pragma unroll
    for (int kk = 0; kk < 8; ++kk) {
        bf16x8 a[2], bfr[2];
#pragma unroll
        for (int f = 0; f < 2; ++f) {
            a[f]   = *reinterpret_cast<const bf16x8*>(&Wt[ar0 + 16 * f + lr][32 * kk + 8 * half]);
            bfr[f] = *reinterpret_cast<const bf16x8*>(&Xt[br0 + 16 * f + lr][32 * kk + 8 * half]);
        }
#pragma unroll
        for (int fa = 0; fa < 2; ++fa)
#pragma unroll
            for (int fb = 0; fb < 2; ++fb)
                acc[fa][fb] = MFMA16(a[fa], bfr[fb], acc[fa][fb], 0, 0, 0);
    }

#pragma unroll
    for (int fa = 0; fa < 2; ++fa)
#pragma unroll
        for (int fb = 0; fb < 2; ++fb) {
            int p = p0 + ar0 + 16 * fa + 4 * half;
            int m = m0 + br0 + 16 * fb + lr;
            f32x4 bias = *reinterpret_cast<const f32x4*>(bp + p);
            f32x4 xr   = *reinterpret_cast<const f32x4*>(x + (size_t)m * NH + p);
            f32x4 out;
#pragma unroll
            for (int r = 0; r < 4; ++r) out[r] = acc[fa][fb][r] + bias[r] + xr[r];
            *reinterpret_cast<f32x4*>(h + (size_t)m * NH + p) = out;
        }
}

// ---------------------------------------------------------------------------
// Kernel 3b: LayerNorm rows of h -> out. One wave per row, shfl reductions.
// ---------------------------------------------------------------------------
__global__ __launch_bounds__(256) void ln_kernel(
    const float* __restrict__ h, const float* __restrict__ gamma,
    const float* __restrict__ beta, float* __restrict__ out)
{
    const int t = threadIdx.x, w = t >> 6, lane = t & 63;
    const size_t row = (size_t)blockIdx.x * 4 + w;
    const float* hr = h + row * NH;
    f32x4 v = *reinterpret_cast<const f32x4*>(hr + lane * 4);
    float s = v[0] + v[1] + v[2] + v[3];
#pragma unroll
    for (int off = 1; off < 64; off <<= 1) s += __shfl_xor(s, off);
    const float mu = s * (1.f / 256.f);
    f32x4 dv; float q = 0.f;
#pragma unroll
    for (int r = 0; r < 4; ++r) { dv[r] = v[r] - mu; q += dv[r] * dv[r]; }
#pragma unroll
    for (int off = 1; off < 64; off <<= 1) q += __shfl_xor(q, off);
    const float rs = rsqrtf(q * (1.f / 256.f) + 1e-5f);
    f32x4 g  = *reinterpret_cast<const f32x4*>(gamma + lane * 4);
    f32x4 be = *reinterpret_cast<const f32x4*>(beta + lane * 4);
    f32x4 o;
#pragma unroll
    for (int r = 0; r < 4; ++r) o[r] = dv[r] * rs * g[r] + be[r];
    *reinterpret_cast<f32x4*>(out + row * NH + lane * 4) = o;
}

extern "C" void kernel_launch(void* const* d_in, const int* in_sizes, int n_in,
                              void* d_out, int out_size, void* d_ws, size_t ws_size,
                              hipStream_t stream)
{
    const float* x     = (const float*)d_in[0];
    const int*   adj   = (const int*)d_in[1];
    const float* Wq    = (const float*)d_in[2];
    const float* Wk    = (const float*)d_in[3];
    const float* Wv    = (const float*)d_in[4];
    const float* Wp    = (const float*)d_in[5];
    const float* bp    = (const float*)d_in[6];
    const float* gamma = (const float*)d_in[7];
    const float* beta  = (const float*)d_in[8];

    char* ws = (char*)d_ws;
    // q/agg overlay at 0 (8MB): q rows are consumed only by the block that
    // rewrites them as agg. k at 8MB, vT at 16MB. h (16MB f32) overlays
    // k+vT after attention. Peak ws use: 24MB.
    unsigned short* qb  = (unsigned short*)(ws);
    unsigned short* kb  = (unsigned short*)(ws + (size_t)8 * 1024 * 1024);
    unsigned short* vT  = (unsigned short*)(ws + (size_t)16 * 1024 * 1024);
    unsigned short* agg = qb;
    float* h = (float*)(ws + (size_t)8 * 1024 * 1024);
    float* out = (float*)d_out;

    qkv_kernel<<<dim3(256, 4, 3), 256, 0, stream>>>(x, Wq, Wk, Wv, qb, kb, vT);
    attn_kernel<<<dim3(256), 256, 0, stream>>>(qb, kb, vT, adj, agg);
    oproj_kernel<<<dim3(256, 4), 256, 0, stream>>>(agg, Wp, bp, x, h);
    ln_kernel<<<dim3(4096), 256, 0, stream>>>(h, gamma, beta, out);
}

// Round 2
// 160.827 us; speedup vs baseline: 1.8818x; 1.8818x over previous
//
#include <hip/hip_runtime.h>
#include <stdint.h>

#define NB 8
#define ND 2048
#define NH 256

typedef __attribute__((ext_vector_type(8))) short bf16x8;
typedef __attribute__((ext_vector_type(4))) float f32x4;
typedef __attribute__((ext_vector_type(4))) int   i32x4;
typedef __attribute__((ext_vector_type(2))) unsigned int u32x2;
typedef __attribute__((ext_vector_type(4))) unsigned int u32x4;

#define MFMA16 __builtin_amdgcn_mfma_f32_16x16x32_bf16

__device__ __forceinline__ unsigned short f2bf(float f) {
    union { float f; unsigned int u; } c; c.f = f;
    unsigned int u = c.u + 0x7FFFu + ((c.u >> 16) & 1u);
    return (unsigned short)(u >> 16);
}
__device__ __forceinline__ unsigned int pack2(float a, float b) {
    return (unsigned int)f2bf(a) | ((unsigned int)f2bf(b) << 16);
}

__device__ __forceinline__ void gload_lds16(const void* g, void* l) {
    __builtin_amdgcn_global_load_lds(
        (const __attribute__((address_space(1))) void*)g,
        (__attribute__((address_space(3))) void*)l, 16, 0, 0);
}

// ---------------------------------------------------------------------------
// Kernel 1: q = x@Wq^T, k = x@Wk^T (row-major bf16), vT[o][d] = (x@Wv^T)^T
// ---------------------------------------------------------------------------
__global__ __launch_bounds__(256) void qkv_kernel(
    const float* __restrict__ x,
    const float* __restrict__ Wq, const float* __restrict__ Wk, const float* __restrict__ Wv,
    unsigned short* __restrict__ qb, unsigned short* __restrict__ kb, unsigned short* __restrict__ vT)
{
    __shared__ unsigned short Wt[64][264];
    __shared__ unsigned short Xt[64][264];
    const int z  = blockIdx.z;
    const int m0 = blockIdx.x * 64;
    const int o0 = blockIdx.y * 64;
    const float* W = (z == 0) ? Wq : (z == 1 ? Wk : Wv);
    const int t = threadIdx.x;

#pragma unroll
    for (int i = 0; i < 16; ++i) {
        int fidx = i * 256 + t;
        int row = fidx >> 6, c4 = fidx & 63;
        f32x4 vW = *reinterpret_cast<const f32x4*>(W + (size_t)(o0 + row) * NH + c4 * 4);
        f32x4 vX = *reinterpret_cast<const f32x4*>(x + (size_t)(m0 + row) * NH + c4 * 4);
        u32x2 pw; pw[0] = pack2(vW[0], vW[1]); pw[1] = pack2(vW[2], vW[3]);
        u32x2 px; px[0] = pack2(vX[0], vX[1]); px[1] = pack2(vX[2], vX[3]);
        *reinterpret_cast<u32x2*>(&Wt[row][c4 * 4]) = pw;
        *reinterpret_cast<u32x2*>(&Xt[row][c4 * 4]) = px;
    }
    __syncthreads();

    const int w = t >> 6, lane = t & 63, lr = lane & 15, half = lane >> 4;
    const unsigned short (*Ab)[264] = (z < 2) ? Wt : Xt;
    const unsigned short (*Bb)[264] = (z < 2) ? Xt : Wt;
    const int ar0 = 32 * (w >> 1), br0 = 32 * (w & 1);

    f32x4 acc[2][2] = {};
#pragma unroll
    for (int kk = 0; kk < 8; ++kk) {
        bf16x8 a[2], bfr[2];
#pragma unroll
        for (int f = 0; f < 2; ++f) {
            a[f]   = *reinterpret_cast<const bf16x8*>(&Ab[ar0 + 16 * f + lr][32 * kk + 8 * half]);
            bfr[f] = *reinterpret_cast<const bf16x8*>(&Bb[br0 + 16 * f + lr][32 * kk + 8 * half]);
        }
#pragma unroll
        for (int fa = 0; fa < 2; ++fa)
#pragma unroll
            for (int fb = 0; fb < 2; ++fb)
                acc[fa][fb] = MFMA16(a[fa], bfr[fb], acc[fa][fb], 0, 0, 0);
    }

    if (z < 2) {
        unsigned short* dst = z ? kb : qb;
#pragma unroll
        for (int fa = 0; fa < 2; ++fa)
#pragma unroll
            for (int fb = 0; fb < 2; ++fb) {
                int m = m0 + br0 + 16 * fb + lr;
                int o = o0 + ar0 + 16 * fa + 4 * half;
                u32x2 pk; pk[0] = pack2(acc[fa][fb][0], acc[fa][fb][1]);
                pk[1] = pack2(acc[fa][fb][2], acc[fa][fb][3]);
                *reinterpret_cast<u32x2*>(dst + (size_t)m * NH + o) = pk;
            }
    } else {
#pragma unroll
        for (int fa = 0; fa < 2; ++fa)
#pragma unroll
            for (int fb = 0; fb < 2; ++fb) {
                int dg = m0 + ar0 + 16 * fa + 4 * half;
                int o  = o0 + br0 + 16 * fb + lr;
                int bb = dg >> 11, di = dg & 2047;
                u32x2 pk; pk[0] = pack2(acc[fa][fb][0], acc[fa][fb][1]);
                pk[1] = pack2(acc[fa][fb][2], acc[fa][fb][3]);
                *reinterpret_cast<u32x2*>(vT + ((size_t)bb * NH + o) * ND + di) = pk;
            }
    }
}

// ---------------------------------------------------------------------------
// Kernel 2: flash attention, LDS-staged K/V with double buffer.
// Block = 4 waves, batch b = bid&7 (XCD swizzle), 64 q-rows.
// Per tile (64 e): stage next K (32KB) + V (32KB) via global_load_lds w/
// inverse-swizzled source; compute QK (4 frags x 8kk), online softmax,
// P via padded per-wave LDS, PV (16 fo x 2 es). One barrier per tile.
// ---------------------------------------------------------------------------
__global__ __launch_bounds__(256, 1) void attn_kernel(
    const unsigned short* __restrict__ qb, const unsigned short* __restrict__ kb,
    const unsigned short* __restrict__ vT, const int* __restrict__ adj,
    unsigned short* __restrict__ agg)
{
    __shared__ unsigned char KT[2][32768];   // [64 e][512 B], swizzled
    __shared__ unsigned char VTl[2][32768];  // [256 o][128 B], swizzled
    __shared__ unsigned short P[4][16][72];  // per-wave, 144B row stride

    const int bid = blockIdx.x;
    const int b = bid & 7, qt = bid >> 3;
    const int t = threadIdx.x, w = t >> 6, lane = t & 63, lr = lane & 15, half = lane >> 4;
    const int d_local = qt * 64 + w * 16 + lr;
    const int swz = (lr & 7) << 4;

    // Q fragments (row d_local, full K=256)
    bf16x8 qf[8];
    const size_t qrow = ((size_t)b * ND + d_local) * NH;
#pragma unroll
    for (int kk = 0; kk < 8; ++kk)
        qf[kk] = *reinterpret_cast<const bf16x8*>(qb + qrow + 32 * kk + 8 * half);

    const char* kbc = (const char*)kb + (size_t)b * ND * 512;       // batch base, bytes
    const char* vtc = (const char*)vT + (size_t)b * NH * ND * 2;    // batch base, bytes
    const int* adjr = adj + ((size_t)b * ND + d_local) * ND;

    // --- staging helpers ---
    auto stageK = [&](int buf, int e0s) {
#pragma unroll
        for (int i = 0; i < 8; ++i) {
            int off = w * 8192 + i * 1024 + lane * 16;
            int r = off >> 9;
            int c = off & 511;
            int src = c ^ ((r & 7) << 4);
            gload_lds16(kbc + (size_t)(e0s + r) * 512 + src,
                        &KT[buf][w * 8192 + i * 1024]);
        }
    };
    auto stageV = [&](int buf, int e0s) {
#pragma unroll
        for (int i = 0; i < 8; ++i) {
            int off = w * 8192 + i * 1024 + lane * 16;
            int o = off >> 7;
            int c = off & 127;
            int src = c ^ ((o & 7) << 4);
            gload_lds16(vtc + (size_t)o * (ND * 2) + e0s * 2 + src,
                        &VTl[buf][w * 8192 + i * 1024]);
        }
    };

    f32x4 acc[16] = {};
    float m_run = -__builtin_inff(), l_run = 0.f;
    const float SC = 0.0625f, L2E = 1.44269504f;

    // prologue: stage tile 0, load adj tile 0
    stageK(0, 0);
    stageV(0, 0);
    i32x4 aj[4];
#pragma unroll
    for (int fe = 0; fe < 4; ++fe)
        aj[fe] = *reinterpret_cast<const i32x4*>(adjr + fe * 16 + 4 * half);
    __syncthreads();   // implies vmcnt(0) drain

    for (int tt = 0; tt < 32; ++tt) {
        const int cur = tt & 1;
        i32x4 ajn[4];
        if (tt < 31) {
            stageK(cur ^ 1, (tt + 1) * 64);
            stageV(cur ^ 1, (tt + 1) * 64);
#pragma unroll
            for (int fe = 0; fe < 4; ++fe)
                ajn[fe] = *reinterpret_cast<const i32x4*>(adjr + (tt + 1) * 64 + fe * 16 + 4 * half);
        }

        // ---- QK^T: S^T frags, 4 independent chains of 8 ----
        const char* Kc = (const char*)&KT[cur][0];
        f32x4 s[4] = {};
#pragma unroll
        for (int kk = 0; kk < 8; ++kk) {
#pragma unroll
            for (int fe = 0; fe < 4; ++fe) {
                bf16x8 kf = *reinterpret_cast<const bf16x8*>(
                    Kc + (fe * 16 + lr) * 512 + ((kk * 64 + half * 16) ^ swz));
                s[fe] = MFMA16(kf, qf[kk], s[fe], 0, 0, 0);
            }
        }

        // ---- mask + online softmax (per-lane d, 16 vals; 4-lane reduce) ----
        float p[4][4];
        float tmax = -__builtin_inff();
#pragma unroll
        for (int fe = 0; fe < 4; ++fe)
#pragma unroll
            for (int r = 0; r < 4; ++r) {
                float sv = s[fe][r] * SC;
                sv = (aj[fe][r] > 0) ? sv : -1e9f;
                p[fe][r] = sv;
                tmax = fmaxf(tmax, sv);
            }
        tmax = fmaxf(tmax, __shfl_xor(tmax, 16));
        tmax = fmaxf(tmax, __shfl_xor(tmax, 32));
        const float m_new = fmaxf(m_run, tmax);
        const float scale = exp2f((m_run - m_new) * L2E);
        float psum = 0.f;
#pragma unroll
        for (int fe = 0; fe < 4; ++fe)
#pragma unroll
            for (int r = 0; r < 4; ++r) {
                float pe = exp2f((p[fe][r] - m_new) * L2E);
                p[fe][r] = pe;
                psum += pe;
            }
        psum += __shfl_xor(psum, 16);
        psum += __shfl_xor(psum, 32);
        l_run = l_run * scale + psum;
        m_run = m_new;
#pragma unroll
        for (int fo = 0; fo < 16; ++fo)
#pragma unroll
            for (int r = 0; r < 4; ++r) acc[fo][r] *= scale;

        // ---- P -> per-wave LDS (bf16), read back as B-fragments ----
#pragma unroll
        for (int fe = 0; fe < 4; ++fe) {
            u32x2 pk; pk[0] = pack2(p[fe][0], p[fe][1]); pk[1] = pack2(p[fe][2], p[fe][3]);
            *reinterpret_cast<u32x2*>(&P[w][lr][fe * 16 + 4 * half]) = pk;
        }
        bf16x8 pf[2];
#pragma unroll
        for (int es = 0; es < 2; ++es)
            pf[es] = *reinterpret_cast<const bf16x8*>(&P[w][lr][es * 32 + 8 * half]);

        // ---- PV: acc[fo] += V_frag(es) * P_frag(es) ----
        const char* Vc = (const char*)&VTl[cur][0];
#pragma unroll
        for (int fo = 0; fo < 16; ++fo) {
#pragma unroll
            for (int es = 0; es < 2; ++es) {
                bf16x8 vf = *reinterpret_cast<const bf16x8*>(
                    Vc + (fo * 16 + lr) * 128 + ((es * 64 + half * 16) ^ swz));
                acc[fo] = MFMA16(vf, pf[es], acc[fo], 0, 0, 0);
            }
        }

#pragma unroll
        for (int fe = 0; fe < 4; ++fe) aj[fe] = ajn[fe];
        __syncthreads();   // drains next-tile staging; protects buffer reuse
    }

    const float inv = 1.f / l_run;
    const size_t mrow = ((size_t)b * ND + d_local) * NH;
#pragma unroll
    for (int fo = 0; fo < 16; ++fo) {
        u32x2 pk; pk[0] = pack2(acc[fo][0] * inv, acc[fo][1] * inv);
        pk[1] = pack2(acc[fo][2] * inv, acc[fo][3] * inv);
        *reinterpret_cast<u32x2*>(agg + mrow + 16 * fo + 4 * half) = pk;
    }
}

// ---------------------------------------------------------------------------
// Kernel 3a: h = agg @ Wp^T + bp + x   (f32 out)
// ---------------------------------------------------------------------------
__global__ __launch_bounds__(256) void oproj_kernel(
    const unsigned short* __restrict__ agg, const float* __restrict__ Wp,
    const float* __restrict__ bp, const float* __restrict__ x, float* __restrict__ h)
{
    __shared__ unsigned short Wt[64][264];
    __shared__ unsigned short Xt[64][264];
    const int m0 = blockIdx.x * 64, p0 = blockIdx.y * 64;
    const int t = threadIdx.x;

#pragma unroll
    for (int i = 0; i < 16; ++i) {
        int fidx = i * 256 + t, row = fidx >> 6, c4 = fidx & 63;
        f32x4 vW = *reinterpret_cast<const f32x4*>(Wp + (size_t)(p0 + row) * NH + c4 * 4);
        u32x2 pw; pw[0] = pack2(vW[0], vW[1]); pw[1] = pack2(vW[2], vW[3]);
        *reinterpret_cast<u32x2*>(&Wt[row][c4 * 4]) = pw;
    }
#pragma unroll
    for (int i = 0; i < 8; ++i) {
        int fidx = i * 256 + t, row = fidx >> 5, c8 = fidx & 31;
        u32x4 vA = *reinterpret_cast<const u32x4*>(agg + (size_t)(m0 + row) * NH + c8 * 8);
        *reinterpret_cast<u32x4*>(&Xt[row][c8 * 8]) = vA;
    }
    __syncthreads();

    const int w = t >> 6, lane = t & 63, lr = lane & 15, half = lane >> 4;
    const int ar0 = 32 * (w >> 1), br0 = 32 * (w & 1);

    f32x4 acc[2][2] = {};
#pragma unroll
    for (int kk = 0; kk < 8; ++kk) {
        bf16x8 a[2], bfr[2];
#pragma unroll
        for (int f = 0; f < 2; ++f) {
            a[f]   = *reinterpret_cast<const bf16x8*>(&Wt[ar0 + 16 * f + lr][32 * kk + 8 * half]);
            bfr[f] = *reinterpret_cast<const bf16x8*>(&Xt[br0 + 16 * f + lr][32 * kk + 8 * half]);
        }
#pragma unroll
        for (int fa = 0; fa < 2; ++fa)
#pragma unroll
            for (int fb = 0; fb < 2; ++fb)
                acc[fa][fb] = MFMA16(a[fa], bfr[fb], acc[fa][fb], 0, 0, 0);
    }

#pragma unroll
    for (int fa = 0; fa < 2; ++fa)
#pragma unroll
        for (int fb = 0; fb < 2; ++fb) {
            int pcol = p0 + ar0 + 16 * fa + 4 * half;
            int m = m0 + br0 + 16 * fb + lr;
            f32x4 bias = *reinterpret_cast<const f32x4*>(bp + pcol);
            f32x4 xr   = *reinterpret_cast<const f32x4*>(x + (size_t)m * NH + pcol);
            f32x4 out;
#pragma unroll
            for (int r = 0; r < 4; ++r) out[r] = acc[fa][fb][r] + bias[r] + xr[r];
            *reinterpret_cast<f32x4*>(h + (size_t)m * NH + pcol) = out;
        }
}

// ---------------------------------------------------------------------------
// Kernel 3b: LayerNorm rows of h -> out.
// ---------------------------------------------------------------------------
__global__ __launch_bounds__(256) void ln_kernel(
    const float* __restrict__ h, const float* __restrict__ gamma,
    const float* __restrict__ beta, float* __restrict__ out)
{
    const int t = threadIdx.x, w = t >> 6, lane = t & 63;
    const size_t row = (size_t)blockIdx.x * 4 + w;
    const float* hr = h + row * NH;
    f32x4 v = *reinterpret_cast<const f32x4*>(hr + lane * 4);
    float s = v[0] + v[1] + v[2] + v[3];
#pragma unroll
    for (int off = 1; off < 64; off <<= 1) s += __shfl_xor(s, off);
    const float mu = s * (1.f / 256.f);
    f32x4 dv; float q = 0.f;
#pragma unroll
    for (int r = 0; r < 4; ++r) { dv[r] = v[r] - mu; q += dv[r] * dv[r]; }
#pragma unroll
    for (int off = 1; off < 64; off <<= 1) q += __shfl_xor(q, off);
    const float rs = rsqrtf(q * (1.f / 256.f) + 1e-5f);
    f32x4 g  = *reinterpret_cast<const f32x4*>(gamma + lane * 4);
    f32x4 be = *reinterpret_cast<const f32x4*>(beta + lane * 4);
    f32x4 o;
#pragma unroll
    for (int r = 0; r < 4; ++r) o[r] = dv[r] * rs * g[r] + be[r];
    *reinterpret_cast<f32x4*>(out + row * NH + lane * 4) = o;
}

extern "C" void kernel_launch(void* const* d_in, const int* in_sizes, int n_in,
                              void* d_out, int out_size, void* d_ws, size_t ws_size,
                              hipStream_t stream)
{
    const float* x     = (const float*)d_in[0];
    const int*   adj   = (const int*)d_in[1];
    const float* Wq    = (const float*)d_in[2];
    const float* Wk    = (const float*)d_in[3];
    const float* Wv    = (const float*)d_in[4];
    const float* Wp    = (const float*)d_in[5];
    const float* bp    = (const float*)d_in[6];
    const float* gamma = (const float*)d_in[7];
    const float* beta  = (const float*)d_in[8];

    char* ws = (char*)d_ws;
    unsigned short* qb  = (unsigned short*)(ws);
    unsigned short* kb  = (unsigned short*)(ws + (size_t)8 * 1024 * 1024);
    unsigned short* vT  = (unsigned short*)(ws + (size_t)16 * 1024 * 1024);
    unsigned short* agg = qb;
    float* h = (float*)(ws + (size_t)8 * 1024 * 1024);
    float* out = (float*)d_out;

    qkv_kernel<<<dim3(256, 4, 3), 256, 0, stream>>>(x, Wq, Wk, Wv, qb, kb, vT);
    attn_kernel<<<dim3(256), 256, 0, stream>>>(qb, kb, vT, adj, agg);
    oproj_kernel<<<dim3(256, 4), 256, 0, stream>>>(agg, Wp, bp, x, h);
    ln_kernel<<<dim3(4096), 256, 0, stream>>>(h, gamma, beta, out);
}

// Round 3
// 150.137 us; speedup vs baseline: 2.0158x; 1.0712x over previous
//
#include <hip/hip_runtime.h>
#include <stdint.h>

#define NB 8
#define ND 2048
#define NH 256

typedef __attribute__((ext_vector_type(8))) short bf16x8;
typedef __attribute__((ext_vector_type(4))) float f32x4;
typedef __attribute__((ext_vector_type(4))) int   i32x4;
typedef __attribute__((ext_vector_type(2))) unsigned int u32x2;
typedef __attribute__((ext_vector_type(4))) unsigned int u32x4;

#define MFMA16 __builtin_amdgcn_mfma_f32_16x16x32_bf16

__device__ __forceinline__ unsigned short f2bf(float f) {
    union { float f; unsigned int u; } c; c.f = f;
    unsigned int u = c.u + 0x7FFFu + ((c.u >> 16) & 1u);
    return (unsigned short)(u >> 16);
}
__device__ __forceinline__ unsigned int pack2(float a, float b) {
    return (unsigned int)f2bf(a) | ((unsigned int)f2bf(b) << 16);
}

__device__ __forceinline__ void gload_lds16(const void* g, void* l) {
    __builtin_amdgcn_global_load_lds(
        (const __attribute__((address_space(1))) void*)g,
        (__attribute__((address_space(3))) void*)l, 16, 0, 0);
}

// ---------------------------------------------------------------------------
// Kernel 1: q = x@Wq^T, k = x@Wk^T (row-major bf16), vT[o][d] = (x@Wv^T)^T
// ---------------------------------------------------------------------------
__global__ __launch_bounds__(256) void qkv_kernel(
    const float* __restrict__ x,
    const float* __restrict__ Wq, const float* __restrict__ Wk, const float* __restrict__ Wv,
    unsigned short* __restrict__ qb, unsigned short* __restrict__ kb, unsigned short* __restrict__ vT)
{
    __shared__ unsigned short Wt[64][264];
    __shared__ unsigned short Xt[64][264];
    const int z  = blockIdx.z;
    const int m0 = blockIdx.x * 64;
    const int o0 = blockIdx.y * 64;
    const float* W = (z == 0) ? Wq : (z == 1 ? Wk : Wv);
    const int t = threadIdx.x;

#pragma unroll
    for (int i = 0; i < 16; ++i) {
        int fidx = i * 256 + t;
        int row = fidx >> 6, c4 = fidx & 63;
        f32x4 vW = *reinterpret_cast<const f32x4*>(W + (size_t)(o0 + row) * NH + c4 * 4);
        f32x4 vX = *reinterpret_cast<const f32x4*>(x + (size_t)(m0 + row) * NH + c4 * 4);
        u32x2 pw; pw[0] = pack2(vW[0], vW[1]); pw[1] = pack2(vW[2], vW[3]);
        u32x2 px; px[0] = pack2(vX[0], vX[1]); px[1] = pack2(vX[2], vX[3]);
        *reinterpret_cast<u32x2*>(&Wt[row][c4 * 4]) = pw;
        *reinterpret_cast<u32x2*>(&Xt[row][c4 * 4]) = px;
    }
    __syncthreads();

    const int w = t >> 6, lane = t & 63, lr = lane & 15, half = lane >> 4;
    const unsigned short (*Ab)[264] = (z < 2) ? Wt : Xt;
    const unsigned short (*Bb)[264] = (z < 2) ? Xt : Wt;
    const int ar0 = 32 * (w >> 1), br0 = 32 * (w & 1);

    f32x4 acc[2][2] = {};
#pragma unroll
    for (int kk = 0; kk < 8; ++kk) {
        bf16x8 a[2], bfr[2];
#pragma unroll
        for (int f = 0; f < 2; ++f) {
            a[f]   = *reinterpret_cast<const bf16x8*>(&Ab[ar0 + 16 * f + lr][32 * kk + 8 * half]);
            bfr[f] = *reinterpret_cast<const bf16x8*>(&Bb[br0 + 16 * f + lr][32 * kk + 8 * half]);
        }
#pragma unroll
        for (int fa = 0; fa < 2; ++fa)
#pragma unroll
            for (int fb = 0; fb < 2; ++fb)
                acc[fa][fb] = MFMA16(a[fa], bfr[fb], acc[fa][fb], 0, 0, 0);
    }

    if (z < 2) {
        unsigned short* dst = z ? kb : qb;
#pragma unroll
        for (int fa = 0; fa < 2; ++fa)
#pragma unroll
            for (int fb = 0; fb < 2; ++fb) {
                int m = m0 + br0 + 16 * fb + lr;
                int o = o0 + ar0 + 16 * fa + 4 * half;
                u32x2 pk; pk[0] = pack2(acc[fa][fb][0], acc[fa][fb][1]);
                pk[1] = pack2(acc[fa][fb][2], acc[fa][fb][3]);
                *reinterpret_cast<u32x2*>(dst + (size_t)m * NH + o) = pk;
            }
    } else {
#pragma unroll
        for (int fa = 0; fa < 2; ++fa)
#pragma unroll
            for (int fb = 0; fb < 2; ++fb) {
                int dg = m0 + ar0 + 16 * fa + 4 * half;
                int o  = o0 + br0 + 16 * fb + lr;
                int bb = dg >> 11, di = dg & 2047;
                u32x2 pk; pk[0] = pack2(acc[fa][fb][0], acc[fa][fb][1]);
                pk[1] = pack2(acc[fa][fb][2], acc[fa][fb][3]);
                *reinterpret_cast<u32x2*>(vT + ((size_t)bb * NH + o) * ND + di) = pk;
            }
    }
}

// ---------------------------------------------------------------------------
// Kernel 2: flash attention. 512 threads = 8 waves. Wave pair (wq, wq+4)
// shares 16 q-rows: QK^T + softmax duplicated, PV/acc split by fo-half.
// K/V LDS-staged, double-buffered, one barrier per tile. Defer-max rescale.
// ---------------------------------------------------------------------------
__global__ __launch_bounds__(512, 2) void attn_kernel(
    const unsigned short* __restrict__ qb, const unsigned short* __restrict__ kb,
    const unsigned short* __restrict__ vT, const int* __restrict__ adj,
    unsigned short* __restrict__ agg)
{
    __shared__ unsigned char KT[2][32768];   // [64 e][512 B], swizzled
    __shared__ unsigned char VTl[2][32768];  // [256 o][128 B], swizzled
    __shared__ unsigned short P[8][16][72];  // per-wave, padded

    const int bid = blockIdx.x;
    const int b = bid & 7, qt = bid >> 3;
    const int t = threadIdx.x, w = t >> 6, lane = t & 63, lr = lane & 15, half = lane >> 4;
    const int wq = w & 3, side = w >> 2;
    const int d_local = qt * 64 + wq * 16 + lr;
    const int swz = (lr & 7) << 4;

    bf16x8 qf[8];
    const size_t qrow = ((size_t)b * ND + d_local) * NH;
#pragma unroll
    for (int kk = 0; kk < 8; ++kk)
        qf[kk] = *reinterpret_cast<const bf16x8*>(qb + qrow + 32 * kk + 8 * half);

    const char* kbc = (const char*)kb + (size_t)b * ND * 512;
    const char* vtc = (const char*)vT + (size_t)b * NH * ND * 2;
    const int* adjr = adj + ((size_t)b * ND + d_local) * ND;

    auto stageK = [&](int buf, int e0s) {
#pragma unroll
        for (int i = 0; i < 4; ++i) {
            int off = w * 4096 + i * 1024 + lane * 16;
            int r = off >> 9;
            int c = off & 511;
            int src = c ^ ((r & 7) << 4);
            gload_lds16(kbc + (size_t)(e0s + r) * 512 + src,
                        &KT[buf][w * 4096 + i * 1024]);
        }
    };
    auto stageV = [&](int buf, int e0s) {
#pragma unroll
        for (int i = 0; i < 4; ++i) {
            int off = w * 4096 + i * 1024 + lane * 16;
            int o = off >> 7;
            int c = off & 127;
            int src = c ^ ((o & 7) << 4);
            gload_lds16(vtc + (size_t)o * (ND * 2) + e0s * 2 + src,
                        &VTl[buf][w * 4096 + i * 1024]);
        }
    };

    f32x4 acc[8] = {};
    float m_run = -__builtin_inff(), l_run = 0.f;
    const float SC = 0.0625f, L2E = 1.44269504f;

    stageK(0, 0);
    stageV(0, 0);
    i32x4 aj[4];
#pragma unroll
    for (int fe = 0; fe < 4; ++fe)
        aj[fe] = *reinterpret_cast<const i32x4*>(adjr + fe * 16 + 4 * half);
    __syncthreads();

    for (int tt = 0; tt < 32; ++tt) {
        const int cur = tt & 1;
        i32x4 ajn[4];
        if (tt < 31) {
            stageK(cur ^ 1, (tt + 1) * 64);
            stageV(cur ^ 1, (tt + 1) * 64);
#pragma unroll
            for (int fe = 0; fe < 4; ++fe)
                ajn[fe] = *reinterpret_cast<const i32x4*>(adjr + (tt + 1) * 64 + fe * 16 + 4 * half);
        }

        // ---- QK^T: S^T frags (duplicated in wave pair) ----
        const char* Kc = (const char*)&KT[cur][0];
        f32x4 s[4] = {};
#pragma unroll
        for (int kk = 0; kk < 8; ++kk) {
#pragma unroll
            for (int fe = 0; fe < 4; ++fe) {
                bf16x8 kf = *reinterpret_cast<const bf16x8*>(
                    Kc + (fe * 16 + lr) * 512 + ((kk * 64 + half * 16) ^ swz));
                s[fe] = MFMA16(kf, qf[kk], s[fe], 0, 0, 0);
            }
        }

        // ---- mask + online softmax with defer-max ----
        float p[4][4];
        float tmax = -__builtin_inff();
#pragma unroll
        for (int fe = 0; fe < 4; ++fe)
#pragma unroll
            for (int r = 0; r < 4; ++r) {
                float sv = s[fe][r] * SC;
                sv = (aj[fe][r] > 0) ? sv : -1e9f;
                p[fe][r] = sv;
                tmax = fmaxf(tmax, sv);
            }
        tmax = fmaxf(tmax, __shfl_xor(tmax, 16));
        tmax = fmaxf(tmax, __shfl_xor(tmax, 32));

        if (!__all(tmax <= m_run + 8.0f)) {
            const float m_new = fmaxf(m_run, tmax);
            const float scale = exp2f((m_run - m_new) * L2E);
#pragma unroll
            for (int fo = 0; fo < 8; ++fo)
#pragma unroll
                for (int r = 0; r < 4; ++r) acc[fo][r] *= scale;
            l_run *= scale;
            m_run = m_new;
        }
        float psum = 0.f;
#pragma unroll
        for (int fe = 0; fe < 4; ++fe)
#pragma unroll
            for (int r = 0; r < 4; ++r) {
                float pe = exp2f((p[fe][r] - m_run) * L2E);
                p[fe][r] = pe;
                psum += pe;
            }
        psum += __shfl_xor(psum, 16);
        psum += __shfl_xor(psum, 32);
        l_run += psum;

        // ---- P -> per-wave LDS (bf16), read back as B-fragments ----
#pragma unroll
        for (int fe = 0; fe < 4; ++fe) {
            u32x2 pk; pk[0] = pack2(p[fe][0], p[fe][1]); pk[1] = pack2(p[fe][2], p[fe][3]);
            *reinterpret_cast<u32x2*>(&P[w][lr][fe * 16 + 4 * half]) = pk;
        }
        bf16x8 pf[2];
#pragma unroll
        for (int es = 0; es < 2; ++es)
            pf[es] = *reinterpret_cast<const bf16x8*>(&P[w][lr][es * 32 + 8 * half]);

        // ---- PV: this wave's fo-half ----
        const char* Vc = (const char*)&VTl[cur][0];
#pragma unroll
        for (int j = 0; j < 8; ++j) {
            const int fo = side * 8 + j;
#pragma unroll
            for (int es = 0; es < 2; ++es) {
                bf16x8 vf = *reinterpret_cast<const bf16x8*>(
                    Vc + (fo * 16 + lr) * 128 + ((es * 64 + half * 16) ^ swz));
                acc[j] = MFMA16(vf, pf[es], acc[j], 0, 0, 0);
            }
        }

        if (tt < 31) {
#pragma unroll
            for (int fe = 0; fe < 4; ++fe) aj[fe] = ajn[fe];
        }
        __syncthreads();
    }

    const float inv = 1.f / l_run;
    const size_t mrow = ((size_t)b * ND + d_local) * NH;
#pragma unroll
    for (int j = 0; j < 8; ++j) {
        const int fo = side * 8 + j;
        u32x2 pk; pk[0] = pack2(acc[j][0] * inv, acc[j][1] * inv);
        pk[1] = pack2(acc[j][2] * inv, acc[j][3] * inv);
        *reinterpret_cast<u32x2*>(agg + mrow + 16 * fo + 4 * half) = pk;
    }
}

// ---------------------------------------------------------------------------
// Kernel 3a: h = agg @ Wp^T + bp + x   (f32 out)
// ---------------------------------------------------------------------------
__global__ __launch_bounds__(256) void oproj_kernel(
    const unsigned short* __restrict__ agg, const float* __restrict__ Wp,
    const float* __restrict__ bp, const float* __restrict__ x, float* __restrict__ h)
{
    __shared__ unsigned short Wt[64][264];
    __shared__ unsigned short Xt[64][264];
    const int m0 = blockIdx.x * 64, p0 = blockIdx.y * 64;
    const int t = threadIdx.x;

#pragma unroll
    for (int i = 0; i < 16; ++i) {
        int fidx = i * 256 + t, row = fidx >> 6, c4 = fidx & 63;
        f32x4 vW = *reinterpret_cast<const f32x4*>(Wp + (size_t)(p0 + row) * NH + c4 * 4);
        u32x2 pw; pw[0] = pack2(vW[0], vW[1]); pw[1] = pack2(vW[2], vW[3]);
        *reinterpret_cast<u32x2*>(&Wt[row][c4 * 4]) = pw;
    }
#pragma unroll
    for (int i = 0; i < 8; ++i) {
        int fidx = i * 256 + t, row = fidx >> 5, c8 = fidx & 31;
        u32x4 vA = *reinterpret_cast<const u32x4*>(agg + (size_t)(m0 + row) * NH + c8 * 8);
        *reinterpret_cast<u32x4*>(&Xt[row][c8 * 8]) = vA;
    }
    __syncthreads();

    const int w = t >> 6, lane = t & 63, lr = lane & 15, half = lane >> 4;
    const int ar0 = 32 * (w >> 1), br0 = 32 * (w & 1);

    f32x4 acc[2][2] = {};
#pragma unroll
    for (int kk = 0; kk < 8; ++kk) {
        bf16x8 a[2], bfr[2];
#pragma unroll
        for (int f = 0; f < 2; ++f) {
            a[f]   = *reinterpret_cast<const bf16x8*>(&Wt[ar0 + 16 * f + lr][32 * kk + 8 * half]);
            bfr[f] = *reinterpret_cast<const bf16x8*>(&Xt[br0 + 16 * f + lr][32 * kk + 8 * half]);
        }
#pragma unroll
        for (int fa = 0; fa < 2; ++fa)
#pragma unroll
            for (int fb = 0; fb < 2; ++fb)
                acc[fa][fb] = MFMA16(a[fa], bfr[fb], acc[fa][fb], 0, 0, 0);
    }

#pragma unroll
    for (int fa = 0; fa < 2; ++fa)
#pragma unroll
        for (int fb = 0; fb < 2; ++fb) {
            int pcol = p0 + ar0 + 16 * fa + 4 * half;
            int m = m0 + br0 + 16 * fb + lr;
            f32x4 bias = *reinterpret_cast<const f32x4*>(bp + pcol);
            f32x4 xr   = *reinterpret_cast<const f32x4*>(x + (size_t)m * NH + pcol);
            f32x4 out;
#pragma unroll
            for (int r = 0; r < 4; ++r) out[r] = acc[fa][fb][r] + bias[r] + xr[r];
            *reinterpret_cast<f32x4*>(h + (size_t)m * NH + pcol) = out;
        }
}

// ---------------------------------------------------------------------------
// Kernel 3b: LayerNorm rows of h -> out.
// ---------------------------------------------------------------------------
__global__ __launch_bounds__(256) void ln_kernel(
    const float* __restrict__ h, const float* __restrict__ gamma,
    const float* __restrict__ beta, float* __restrict__ out)
{
    const int t = threadIdx.x, w = t >> 6, lane = t & 63;
    const size_t row = (size_t)blockIdx.x * 4 + w;
    const float* hr = h + row * NH;
    f32x4 v = *reinterpret_cast<const f32x4*>(hr + lane * 4);
    float s = v[0] + v[1] + v[2] + v[3];
#pragma unroll
    for (int off = 1; off < 64; off <<= 1) s += __shfl_xor(s, off);
    const float mu = s * (1.f / 256.f);
    f32x4 dv; float q = 0.f;
#pragma unroll
    for (int r = 0; r < 4; ++r) { dv[r] = v[r] - mu; q += dv[r] * dv[r]; }
#pragma unroll
    for (int off = 1; off < 64; off <<= 1) q += __shfl_xor(q, off);
    const float rs = rsqrtf(q * (1.f / 256.f) + 1e-5f);
    f32x4 g  = *reinterpret_cast<const f32x4*>(gamma + lane * 4);
    f32x4 be = *reinterpret_cast<const f32x4*>(beta + lane * 4);
    f32x4 o;
#pragma unroll
    for (int r = 0; r < 4; ++r) o[r] = dv[r] * rs * g[r] + be[r];
    *reinterpret_cast<f32x4*>(out + row * NH + lane * 4) = o;
}

extern "C" void kernel_launch(void* const* d_in, const int* in_sizes, int n_in,
                              void* d_out, int out_size, void* d_ws, size_t ws_size,
                              hipStream_t stream)
{
    const float* x     = (const float*)d_in[0];
    const int*   adj   = (const int*)d_in[1];
    const float* Wq    = (const float*)d_in[2];
    const float* Wk    = (const float*)d_in[3];
    const float* Wv    = (const float*)d_in[4];
    const float* Wp    = (const float*)d_in[5];
    const float* bp    = (const float*)d_in[6];
    const float* gamma = (const float*)d_in[7];
    const float* beta  = (const float*)d_in[8];

    char* ws = (char*)d_ws;
    unsigned short* qb  = (unsigned short*)(ws);
    unsigned short* kb  = (unsigned short*)(ws + (size_t)8 * 1024 * 1024);
    unsigned short* vT  = (unsigned short*)(ws + (size_t)16 * 1024 * 1024);
    unsigned short* agg = qb;
    float* h = (float*)(ws + (size_t)8 * 1024 * 1024);
    float* out = (float*)d_out;

    qkv_kernel<<<dim3(256, 4, 3), 256, 0, stream>>>(x, Wq, Wk, Wv, qb, kb, vT);
    attn_kernel<<<dim3(256), 512, 0, stream>>>(qb, kb, vT, adj, agg);
    oproj_kernel<<<dim3(256, 4), 256, 0, stream>>>(agg, Wp, bp, x, h);
    ln_kernel<<<dim3(4096), 256, 0, stream>>>(h, gamma, beta, out);
}